// Round 7
// baseline (488.799 us; speedup 1.0000x reference)
//
#include <hip/hip_runtime.h>

#define D 256
#define H 256
#define O 24
#define R 64          // rows per block
#define T 512         // 8 waves; wave = 64 rows x 32 cols
#define PW 264        // ushort row stride (528 B, 16B-aligned)
#define PS (R * PW)   // piece stride (ushorts)
#define LSCALE 4096.0f
#define INV_LSCALE (1.0f / 4096.0f)
#define GAP_EPS 1e-3f

typedef __attribute__((ext_vector_type(4))) float f32x4;
typedef __attribute__((ext_vector_type(4))) unsigned short us4;
typedef __attribute__((ext_vector_type(8))) unsigned short us8;
typedef __attribute__((ext_vector_type(8))) _Float16 f16x8;
typedef __attribute__((ext_vector_type(4))) unsigned int u32x4;

// d_ws layout (ushort units): fp16 2-piece fragments, tile(kb,nb) base =
// ((kb*NB+nb)*2 + piece)*512 + lane*8 + j.
//   wf1 @ 0 (256 KB) | wf2 @ 131072 (256 KB) | wf3 @ 262144 (32 KB)
//   flags (u32[4096], 1 bit/row) @ byte offset 557056
#define WF2_OFF 131072
#define WF3_OFF 262144
#define FLAGS_BYTE_OFF 557056

// fp16 2-piece split; l scaled by 2^12 to stay in fp16 normal range.
// v ≈ h + l*2^-12 with error ≤ 2^-22 |v|.
__device__ __forceinline__ void split2(float v, unsigned short& h, unsigned short& l) {
    _Float16 hh = (_Float16)v;
    float r = (v - (float)hh) * LSCALE;   // exact subtract, exact pow2 scale
    _Float16 ll = (_Float16)r;
    h = __builtin_bit_cast(unsigned short, hh);
    l = __builtin_bit_cast(unsigned short, ll);
}

__device__ __forceinline__ f32x4 mfma_f16(us8 a, us8 b, f32x4 c) {
    return __builtin_amdgcn_mfma_f32_16x16x32_f16(
        __builtin_bit_cast(f16x8, a), __builtin_bit_cast(f16x8, b), c, 0, 0, 0);
}

// ---- pre-split W1/W2/W3 into B-fragment-linear fp16 pieces ----
__global__ void split_w(const float* __restrict__ W1, const float* __restrict__ W2,
                        const float* __restrict__ W3, unsigned short* __restrict__ wf)
{
    const int bid = blockIdx.x;        // 0..271
    const int lane = threadIdx.x;      // 0..63
    const int q = lane >> 4, ln = lane & 15;
    const float* src; unsigned short* dst; int nbcnt, ld, ncols, kb, nb;
    if (bid < 128) {
        src = W1; dst = wf; nbcnt = 16; ld = H; ncols = H;
        kb = bid >> 4; nb = bid & 15;
    } else if (bid < 256) {
        src = W2; dst = wf + WF2_OFF; nbcnt = 16; ld = H; ncols = H;
        kb = (bid - 128) >> 4; nb = bid & 15;
    } else {
        int b = bid - 256; src = W3; dst = wf + WF3_OFF; nbcnt = 2; ld = O; ncols = O;
        kb = b >> 1; nb = b & 1;
    }
    const int n = nb * 16 + ln;
    #pragma unroll
    for (int j = 0; j < 8; ++j) {
        const int k = kb * 32 + q * 8 + j;
        float v = (n < ncols) ? src[(size_t)k * ld + n] : 0.f;
        unsigned short h, l; split2(v, h, l);
        size_t base = (size_t)((kb * nbcnt + nb) * 2) * 512 + (size_t)lane * 8 + j;
        dst[base] = h; dst[base + 512] = l;
    }
}

// One layer: wave computes 64 rows x its 2 col-tiles; in-place piece update.
__device__ __forceinline__ void layer_fwd(unsigned short* pb, const u32x4* __restrict__ wfL,
                                          const float* __restrict__ bias, int nb0, int lane)
{
    const int ln = lane & 15, q = lane >> 4;
    f32x4 acch[4][2], accl[4][2];
    #pragma unroll
    for (int nb = 0; nb < 2; ++nb) {
        const float bv = bias[(nb0 + nb) * 16 + ln];
        #pragma unroll
        for (int rt = 0; rt < 4; ++rt) {
            acch[rt][nb] = (f32x4){bv, bv, bv, bv};
            accl[rt][nb] = (f32x4){0.f, 0.f, 0.f, 0.f};
        }
    }
    #pragma unroll 2
    for (int kb = 0; kb < 8; ++kb) {
        us8 bh[2], bl[2];
        #pragma unroll
        for (int nb = 0; nb < 2; ++nb) {
            const size_t tb = (size_t)((kb * 16 + nb0 + nb) * 2) * 64 + lane;
            bh[nb] = __builtin_bit_cast(us8, wfL[tb]);
            bl[nb] = __builtin_bit_cast(us8, wfL[tb + 64]);
        }
        #pragma unroll
        for (int rt = 0; rt < 4; ++rt) {
            const unsigned short* ap = pb + (size_t)(rt * 16 + ln) * PW + kb * 32 + q * 8;
            us8 ah = *(const us8*)ap;          // ds_read_b128
            us8 al = *(const us8*)(ap + PS);
            #pragma unroll
            for (int nb = 0; nb < 2; ++nb) {
                acch[rt][nb] = mfma_f16(ah, bh[nb], acch[rt][nb]);
                accl[rt][nb] = mfma_f16(al, bh[nb], accl[rt][nb]);
                accl[rt][nb] = mfma_f16(ah, bl[nb], accl[rt][nb]);
            }
        }
    }
    __syncthreads();   // all reads of previous activations done
    #pragma unroll
    for (int rt = 0; rt < 4; ++rt)
        #pragma unroll
        for (int nb = 0; nb < 2; ++nb)
            #pragma unroll
            for (int rg = 0; rg < 4; ++rg) {
                float v = fmaxf(acch[rt][nb][rg] + accl[rt][nb][rg] * INV_LSCALE, 0.f);
                unsigned short h, l; split2(v, h, l);
                const size_t off = (size_t)(rt * 16 + q * 4 + rg) * PW + (nb0 + nb) * 16 + ln;
                pb[off] = h; pb[PS + off] = l;
            }
    __syncthreads();
}

__global__ __launch_bounds__(T, 4) void fused_mlp_topk(
    const float* __restrict__ x,
    const float* __restrict__ b1, const float* __restrict__ b2, const float* __restrict__ b3,
    const u32x4* __restrict__ wfrag, unsigned* __restrict__ flags,
    float* __restrict__ out)
{
    __shared__ __align__(16) unsigned short pbuf[2][R][PW];   // 67584 B
    __shared__ float logitsB[R][25];                          // 6400 B
    __shared__ unsigned selmask[R];                           // 256 B

    const int t = threadIdx.x;
    const int lane = t & 63, w = t >> 6;
    const int ln = lane & 15, q = lane >> 4;
    const long row0 = (long)blockIdx.x * R;
    unsigned short* pb = &pbuf[0][0][0];

    // ---- stage + split x (coalesced f32x4 reads; per-wave single-row b64 LDS writes) ----
    #pragma unroll
    for (int it = 0; it < 8; ++it) {
        const int idx = it * T + t;
        const int row = idx >> 6;
        const int c4 = (idx & 63) * 4;
        f32x4 v = *(const f32x4*)(x + (row0 + row) * D + c4);
        us4 ph, plo;
        #pragma unroll
        for (int j = 0; j < 4; ++j) {
            unsigned short h, l; split2(v[j], h, l);
            ph[j] = h; plo[j] = l;
        }
        *(us4*)(pb + (size_t)row * PW + c4) = ph;
        *(us4*)(pb + PS + (size_t)row * PW + c4) = plo;
    }
    __syncthreads();

    const int nb0 = 2 * w;   // this wave's two col-tiles

    layer_fwd(pb, wfrag, b1, nb0, lane);                 // Layer 1
    layer_fwd(pb, wfrag + WF2_OFF / 8, b2, nb0, lane);   // Layer 2

    // ---- Layer 3: wave w -> row-tile (w>>1), col-tile (w&1) ----
    {
        const int rt3 = w >> 1, nb3 = w & 1;
        const int c = nb3 * 16 + ln;
        const float bv = (c < O) ? b3[c] : 0.f;
        f32x4 a3h = (f32x4){bv, bv, bv, bv};
        f32x4 a3l = (f32x4){0.f, 0.f, 0.f, 0.f};
        const u32x4* wf3 = wfrag + WF3_OFF / 8;
        #pragma unroll 2
        for (int kb = 0; kb < 8; ++kb) {
            const size_t tb = (size_t)((kb * 2 + nb3) * 2) * 64 + lane;
            us8 bh = __builtin_bit_cast(us8, wf3[tb]);
            us8 bl = __builtin_bit_cast(us8, wf3[tb + 64]);
            const unsigned short* ap = pb + (size_t)(rt3 * 16 + ln) * PW + kb * 32 + q * 8;
            us8 ah = *(const us8*)ap;
            us8 al = *(const us8*)(ap + PS);
            a3h = mfma_f16(ah, bh, a3h);
            a3l = mfma_f16(al, bh, a3l);
            a3l = mfma_f16(ah, bl, a3l);
        }
        if (c < O) {
            #pragma unroll
            for (int rg = 0; rg < 4; ++rg)
                logitsB[rt3 * 16 + q * 4 + rg][c] = a3h[rg] + a3l[rg] * INV_LSCALE;
        }
    }
    __syncthreads();

    // ---- top-6 of 22 selected cols + near-tie gap flagging ----
    if (t < R) {
        float v[22];
        #pragma unroll
        for (int i = 0; i < 22; ++i) {
            const int j = (i < 11) ? (i + 1) : (i + 2);
            v[i] = logitsB[t][j];
        }
        unsigned taken = 0u;
        unsigned cm = 1u | (1u << 12);
        float best = 0.f;
        for (int kk = 0; kk < 6; ++kk) {
            best = -3.4e38f; int bi = 0;
            #pragma unroll
            for (int i = 0; i < 22; ++i) {
                if (!((taken >> i) & 1u) && v[i] > best) { best = v[i]; bi = i; }
            }
            taken |= 1u << bi;
            cm |= 1u << ((bi < 11) ? (bi + 1) : (bi + 2));
        }
        float m7 = -3.4e38f;
        #pragma unroll
        for (int i = 0; i < 22; ++i)
            if (!((taken >> i) & 1u)) m7 = fmaxf(m7, v[i]);
        selmask[t] = cm;
        if (best - m7 < GAP_EPS) {
            const unsigned gr = (unsigned)(row0 + t);
            atomicOr(&flags[gr >> 5], 1u << (gr & 31));
        }
    }
    __syncthreads();

    // ---- write mask (coalesced) ----
    #pragma unroll
    for (int i = 0; i < (R * O) / T; ++i) {
        const int idx = i * T + t;
        const int r = idx / O;
        const int j = idx - r * O;
        out[row0 * O + idx] = ((selmask[r] >> j) & 1u) ? 1.0f : 0.0f;
    }
}

// ---- fp64 exact recompute of flagged (near-tie) rows; overwrites out ----
__global__ void refine_rows(const float* __restrict__ x,
                            const float* __restrict__ W1, const float* __restrict__ b1,
                            const float* __restrict__ W2, const float* __restrict__ b2,
                            const float* __restrict__ W3, const float* __restrict__ b3,
                            const unsigned* __restrict__ flags, float* __restrict__ out)
{
    const int grp = blockIdx.x;                  // 64 rows per block, 1 wave
    const unsigned f0 = flags[grp * 2];
    const unsigned f1 = flags[grp * 2 + 1];
    if (!(f0 | f1)) return;

    __shared__ double dh[2][H];
    __shared__ double lg[22];
    __shared__ unsigned cmsh;
    const int lane = threadIdx.x;
    const int c0 = lane * 4;

    unsigned long long fm = ((unsigned long long)f1 << 32) | (unsigned long long)f0;
    while (fm) {
        const int rr = __ffsll((long long)fm) - 1;
        fm &= fm - 1;
        const long row = (long)grp * 64 + rr;
        const float* xr = x + row * D;

        {   // layer 1 (fp64 accum)
            double s0 = b1[c0], s1 = b1[c0 + 1], s2 = b1[c0 + 2], s3 = b1[c0 + 3];
            for (int k = 0; k < D; ++k) {
                const double xv = (double)xr[k];
                const float* wr = W1 + (size_t)k * H + c0;
                s0 = fma(xv, (double)wr[0], s0);
                s1 = fma(xv, (double)wr[1], s1);
                s2 = fma(xv, (double)wr[2], s2);
                s3 = fma(xv, (double)wr[3], s3);
            }
            dh[0][c0] = s0 > 0. ? s0 : 0.; dh[0][c0 + 1] = s1 > 0. ? s1 : 0.;
            dh[0][c0 + 2] = s2 > 0. ? s2 : 0.; dh[0][c0 + 3] = s3 > 0. ? s3 : 0.;
        }
        __syncthreads();
        {   // layer 2
            double s0 = b2[c0], s1 = b2[c0 + 1], s2 = b2[c0 + 2], s3 = b2[c0 + 3];
            for (int k = 0; k < H; ++k) {
                const double hv = dh[0][k];
                const float* wr = W2 + (size_t)k * H + c0;
                s0 = fma(hv, (double)wr[0], s0);
                s1 = fma(hv, (double)wr[1], s1);
                s2 = fma(hv, (double)wr[2], s2);
                s3 = fma(hv, (double)wr[3], s3);
            }
            dh[1][c0] = s0 > 0. ? s0 : 0.; dh[1][c0 + 1] = s1 > 0. ? s1 : 0.;
            dh[1][c0 + 2] = s2 > 0. ? s2 : 0.; dh[1][c0 + 3] = s3 > 0. ? s3 : 0.;
        }
        __syncthreads();
        if (lane < 22) {   // selected logits
            const int j = (lane < 11) ? (lane + 1) : (lane + 2);
            double s = b3[j];
            for (int k = 0; k < H; ++k)
                s = fma(dh[1][k], (double)W3[(size_t)k * O + j], s);
            lg[lane] = s;
        }
        __syncthreads();
        if (lane == 0) {   // serial top-6, lowest-index tie-break
            unsigned taken = 0u, cm = 1u | (1u << 12);
            for (int kk = 0; kk < 6; ++kk) {
                double best = -1e300; int bi = 0;
                for (int i = 0; i < 22; ++i)
                    if (!((taken >> i) & 1u) && lg[i] > best) { best = lg[i]; bi = i; }
                taken |= 1u << bi;
                cm |= 1u << ((bi < 11) ? (bi + 1) : (bi + 2));
            }
            cmsh = cm;
        }
        __syncthreads();
        if (lane < O)
            out[row * O + lane] = ((cmsh >> lane) & 1u) ? 1.0f : 0.0f;
        __syncthreads();
    }
}

extern "C" void kernel_launch(void* const* d_in, const int* in_sizes, int n_in,
                              void* d_out, int out_size, void* d_ws, size_t ws_size,
                              hipStream_t stream) {
    const float* x  = (const float*)d_in[0];
    const float* W1 = (const float*)d_in[1];
    const float* b1 = (const float*)d_in[2];
    const float* W2 = (const float*)d_in[3];
    const float* b2 = (const float*)d_in[4];
    const float* W3 = (const float*)d_in[5];
    const float* b3 = (const float*)d_in[6];
    float* out = (float*)d_out;

    unsigned short* wf = (unsigned short*)d_ws;
    unsigned* flags = (unsigned*)((char*)d_ws + FLAGS_BYTE_OFF);
    const int B = in_sizes[0] / D;   // 131072
    const int nblk = B / R;          // 2048

    hipMemsetAsync(flags, 0, (B / 32) * sizeof(unsigned), stream);
    hipLaunchKernelGGL(split_w, dim3(272), dim3(64), 0, stream, W1, W2, W3, wf);
    hipLaunchKernelGGL(fused_mlp_topk, dim3(nblk), dim3(T), 0, stream,
                       x, b1, b2, b3, (const u32x4*)d_ws, flags, out);
    hipLaunchKernelGGL(refine_rows, dim3(B / 64), dim3(64), 0, stream,
                       x, W1, b1, W2, b2, W3, b3, flags, out);
}